// Round 1
// baseline (354.300 us; speedup 1.0000x reference)
//
#include <hip/hip_runtime.h>
#include <cstdint>
#include <cstddef>

typedef _Float16 f16;
typedef _Float16 f16x8 __attribute__((ext_vector_type(8)));
typedef float f32x4 __attribute__((ext_vector_type(4)));

#define NB_TOT   2048
#define F0_      39
#define DDIM     32
#define HROW     104           // padded hidden row (f16 elems), 208B: 16B-aligned rows, 2-way bank alias only
#define HBATCH   (DDIM*HROW)   // 3328 f16 per batch
#define MT_      13            // 13 x 16 = 208 output rows (200 real)
#define SROW     40            // slab row length in f16 (80B, 16B aligned, 2-way alias)
#define SLAB_F16S 8704         // f16 per K-step slab incl tail pad (= 17408 B = 1088 x 16B)
#define SLAB_BYTES 17408
#define SLAB_CHUNKS 1088

// workspace layout (bytes)
#define SZ_H     ((size_t)NB_TOT*HBATCH*2)     // 13,631,488
#define OFF_H0   ((size_t)0)
#define OFF_H1   (OFF_H0 + SZ_H)
#define OFF_H2   (OFF_H1 + SZ_H)
#define OFF_W0   (OFF_H2 + SZ_H)
#define SZ_W0    ((size_t)49*SLAB_BYTES)
#define OFF_W1   (OFF_W0 + SZ_W0)
#define SZ_W12   ((size_t)127*SLAB_BYTES)
#define OFF_W2   (OFF_W1 + SZ_W12)
#define OFF_BIAS (OFF_W2 + SZ_W12)

// ---------------- prep kernels ----------------

// h0[b][d][n] = (n<39) ? x[b][n][d] : 0   (fp16, transposed, zero-padded)
__global__ void k_prep_h0(const float* __restrict__ x, f16* __restrict__ h0) {
    long idx = (long)blockIdx.x * 256 + threadIdx.x;
    if (idx >= (long)NB_TOT * HBATCH) return;
    int n = (int)(idx % HROW);
    long t = idx / HROW;
    int d = (int)(t % DDIM);
    long b = t / DDIM;
    float v = 0.f;
    if (n < F0_) v = x[(b * F0_ + n) * DDIM + d];
    h0[idx] = (f16)v;
}

// slab[step][o][k] = W[m*hn+n][o] with c' = step*32+k, r=c'>>3, j=c'&7, m=r/runs, n=(r%runs)*8+j
// zeros for: k in [32,40), o>=200, m>=39, n>=hn, and the 768B tail pad of each step
__global__ void k_prep_w(const float* __restrict__ W, f16* __restrict__ slab,
                         int nsteps, int runs, int hn) {
    long idx = (long)blockIdx.x * 256 + threadIdx.x;
    if (idx >= (long)nsteps * SLAB_F16S) return;
    int e = (int)(idx % SLAB_F16S);
    int step = (int)(idx / SLAB_F16S);
    float v = 0.f;
    if (e < 208 * SROW) {
        int o = e / SROW;
        int k = e % SROW;
        if (k < 32 && o < 200) {
            int cp = step * 32 + k;
            int r = cp >> 3;
            int j = cp & 7;
            int m = r / runs;
            int n = (r - m * runs) * 8 + j;
            if (m < F0_ && n < hn)
                v = W[((long)m * hn + n) * 200 + o];
        }
    }
    slab[idx] = (f16)v;
}

__global__ void k_prep_bias(const float* __restrict__ b0, const float* __restrict__ b1,
                            const float* __restrict__ b2, float* __restrict__ dst) {
    int idx = blockIdx.x * 256 + threadIdx.x;
    if (idx >= 3 * 208) return;
    int L = idx / 208, o = idx % 208;
    const float* s = (L == 0) ? b0 : (L == 1 ? b1 : b2);
    dst[idx] = (o < 200) ? s[o] : 0.f;
}

// ---------------- main layer kernel ----------------

__device__ __forceinline__ void gl_lds16(const void* g, void* l) {
    __builtin_amdgcn_global_load_lds(
        (const __attribute__((address_space(1))) unsigned int*)g,
        (__attribute__((address_space(3))) unsigned int*)l,
        16, 0, 0);
}

__device__ __forceinline__ void stage_slab(const f16* __restrict__ slabg, f16* lds,
                                           int step, int tid) {
    const char* g = (const char*)slabg + (size_t)step * SLAB_BYTES;
    char* l = (char*)lds;
#pragma unroll
    for (int rr = 0; rr < 4; ++rr) {
        int idx = rr * 256 + tid;                  // lds dest = wave-uniform base + lane*16
        gl_lds16(g + (size_t)idx * 16, l + (size_t)idx * 16);
    }
    if (tid < 64) {                                 // tail 64 chunks: wave 0 only
        int idx = 1024 + tid;
        gl_lds16(g + (size_t)idx * 16, l + (size_t)idx * 16);
    }
}

// one wave per batch; M=208 (13 tiles), N=32 (2 tiles), K = nsteps*32
template <int RUNS>
__global__ __launch_bounds__(256, 2) void k_layer(
    const f16* __restrict__ xg,     // transposed x (= h0 buffer), [2048][32][104]
    const f16* __restrict__ hg,     // hidden input, same layout
    const f16* __restrict__ slabg,  // [nsteps][8704] f16
    const float* __restrict__ biasg,// [208], zero-padded
    f16* __restrict__ houtg,        // next hidden (or nullptr)
    float* __restrict__ outg,       // d_out [2048][400]
    int nsteps, int direct_lo, int outbase) {
    __shared__ __align__(16) f16 slab_lds[2][SLAB_F16S];
    __shared__ __align__(16) f16 hl[4][HBATCH];

    const int tid = threadIdx.x;
    const int w = tid >> 6;
    const int lane = tid & 63;
    const int b = blockIdx.x * 4 + w;
    const int quad = lane >> 4;
    const int d0 = lane & 15;

    // stage this wave's hidden (coalesced u32 copy)
    {
        const unsigned int* src = (const unsigned int*)(hg + (size_t)b * HBATCH);
        unsigned int* dst = (unsigned int*)&hl[w][0];
        for (int i = lane; i < HBATCH / 2; i += 64) dst[i] = src[i];
    }
    stage_slab(slabg, &slab_lds[0][0], 0, tid);
    __syncthreads();

    f32x4 acc[MT_][2];
#pragma unroll
    for (int mt = 0; mt < MT_; ++mt) {
        acc[mt][0] = (f32x4)0.f;
        acc[mt][1] = (f32x4)0.f;
    }

    const f16* xrow = xg + (size_t)b * HBATCH;

    // software-pipelined x loads for step 0
    int r = quad;
    int m = r / RUNS;
    int nb = (r - m * RUNS) * 8;
    f16 xa = xrow[d0 * HROW + m];
    f16 xb = xrow[(d0 + 16) * HROW + m];

    for (int step = 0; step < nsteps; ++step) {
        const int buf = step & 1;
        const bool more = (step + 1 < nsteps);
        if (more) stage_slab(slabg, &slab_lds[buf ^ 1][0], step + 1, tid);

        // prefetch next step's x scalars (global, latency hidden under MFMAs)
        int r2 = r + 4;
        int m2 = r2 / RUNS;
        int nb2 = (r2 - m2 * RUNS) * 8;
        f16 xa2 = (f16)0.f, xb2 = (f16)0.f;
        if (more) {
            xa2 = xrow[d0 * HROW + m2];
            xb2 = xrow[(d0 + 16) * HROW + m2];
        }

        // build B fragments: Z[k][col] = x[m,d] * h[n,d]
        f16x8 h0v = *(const f16x8*)&hl[w][d0 * HROW + nb];
        f16x8 h1v = *(const f16x8*)&hl[w][(d0 + 16) * HROW + nb];
        f16x8 bb0 = h0v * xa;
        f16x8 bb1 = h1v * xb;

#pragma unroll
        for (int mt = 0; mt < MT_; ++mt) {
            f16x8 a = *(const f16x8*)&slab_lds[buf][(mt * 16 + d0) * SROW + quad * 8];
            acc[mt][0] = __builtin_amdgcn_mfma_f32_16x16x32_f16(a, bb0, acc[mt][0], 0, 0, 0);
            acc[mt][1] = __builtin_amdgcn_mfma_f32_16x16x32_f16(a, bb1, acc[mt][1], 0, 0, 0);
        }

        r = r2; m = m2; nb = nb2; xa = xa2; xb = xb2;
        __syncthreads();
    }

    // -------- epilogue --------
    const bool wrh = (houtg != nullptr);
    f16* scratch = ((f16*)slab_lds) + w * HBATCH;  // 4*6656B <= 34816B: safe reuse after loop
    if (wrh) {
        unsigned int* sz = (unsigned int*)scratch;
        for (int i = lane; i < HBATCH / 2; i += 64) sz[i] = 0u;
    }
    __syncthreads();

#pragma unroll
    for (int mt = 0; mt < MT_; ++mt) {
        float v[2][4];
#pragma unroll
        for (int nt = 0; nt < 2; ++nt)
#pragma unroll
            for (int i = 0; i < 4; ++i) {
                int o = mt * 16 + quad * 4 + i;
                float t = acc[mt][nt][i] + biasg[o];
                v[nt][i] = t > 0.f ? t : 0.f;
            }
        if (wrh && mt < 7) {  // hidden = cur[0:100] -> scratch[d][o] (fp16 transposed)
#pragma unroll
            for (int nt = 0; nt < 2; ++nt)
#pragma unroll
                for (int i = 0; i < 4; ++i) {
                    int o = mt * 16 + quad * 4 + i;
                    if (o < 100) scratch[(d0 + 16 * nt) * HROW + o] = (f16)v[nt][i];
                }
        }
        // sum over all 32 d: nt0+nt1, then butterfly across the 16 d-lanes
        float s[4];
#pragma unroll
        for (int i = 0; i < 4; ++i) s[i] = v[0][i] + v[1][i];
#pragma unroll
        for (int mask = 1; mask <= 8; mask <<= 1)
#pragma unroll
            for (int i = 0; i < 4; ++i) s[i] += __shfl_xor(s[i], mask, 64);
        if (d0 == 0) {
#pragma unroll
            for (int i = 0; i < 4; ++i) {
                int o = mt * 16 + quad * 4 + i;
                if (o >= direct_lo && o < 200)
                    outg[(size_t)b * 400 + outbase + (o - direct_lo)] = s[i];
            }
        }
    }

    if (wrh) {
        __syncthreads();
        const unsigned int* s2 = (const unsigned int*)scratch;
        unsigned int* dg = (unsigned int*)(houtg + (size_t)b * HBATCH);
        for (int i = lane; i < HBATCH / 2; i += 64) dg[i] = s2[i];
    }
}

// ---------------- launch ----------------

extern "C" void kernel_launch(void* const* d_in, const int* in_sizes, int n_in,
                              void* d_out, int out_size, void* d_ws, size_t ws_size,
                              hipStream_t stream) {
    const float* x  = (const float*)d_in[0];
    const float* W0 = (const float*)d_in[1];
    const float* b0 = (const float*)d_in[2];
    const float* W1 = (const float*)d_in[3];
    const float* b1 = (const float*)d_in[4];
    const float* W2 = (const float*)d_in[5];
    const float* b2 = (const float*)d_in[6];
    float* out = (float*)d_out;
    char* ws = (char*)d_ws;

    f16* h0 = (f16*)(ws + OFF_H0);
    f16* h1 = (f16*)(ws + OFF_H1);
    f16* h2 = (f16*)(ws + OFF_H2);
    f16* w0s = (f16*)(ws + OFF_W0);
    f16* w1s = (f16*)(ws + OFF_W1);
    f16* w2s = (f16*)(ws + OFF_W2);
    float* biasws = (float*)(ws + OFF_BIAS);

    {
        long tot = (long)NB_TOT * HBATCH;
        k_prep_h0<<<(unsigned)((tot + 255) / 256), 256, 0, stream>>>(x, h0);
    }
    k_prep_w<<<(unsigned)(((long)49 * SLAB_F16S + 255) / 256), 256, 0, stream>>>(W0, w0s, 49, 5, 39);
    k_prep_w<<<(unsigned)(((long)127 * SLAB_F16S + 255) / 256), 256, 0, stream>>>(W1, w1s, 127, 13, 100);
    k_prep_w<<<(unsigned)(((long)127 * SLAB_F16S + 255) / 256), 256, 0, stream>>>(W2, w2s, 127, 13, 100);
    k_prep_bias<<<3, 256, 0, stream>>>(b0, b1, b2, biasws);

    // layer 0: hidden=x (Hn=39, RUNS=5, 49 K-steps); direct = cur[100:200] -> out[:,0:100)
    k_layer<5><<<512, 256, 0, stream>>>(h0, h0, w0s, biasws + 0, h1, out, 49, 100, 0);
    // layer 1: Hn=100; direct = cur[100:200] -> out[:,100:200)
    k_layer<13><<<512, 256, 0, stream>>>(h0, h1, w1s, biasws + 208, h2, out, 127, 100, 100);
    // layer 2: Hn=100; direct = full cur -> out[:,200:400)
    k_layer<13><<<512, 256, 0, stream>>>(h0, h2, w2s, biasws + 416, (f16*)nullptr, out, 127, 0, 200);
}